// Round 3
// baseline (521.655 us; speedup 1.0000x reference)
//
#include <hip/hip_runtime.h>
#include <hip/hip_bf16.h>
#include <stdint.h>

#define TOKENS 8192
#define HD     2048
#define NE     8

typedef __attribute__((ext_vector_type(8))) short short8;
typedef __attribute__((ext_vector_type(4))) float f32x4;

__device__ __forceinline__ unsigned short f2bf_rne(float f) {
  union { float f; unsigned u; } v; v.f = f;
  unsigned u = v.u;
  return (unsigned short)((u + 0x7fffu + ((u >> 16) & 1u)) >> 16);
}

__device__ __forceinline__ void async_load16(const void* g, void* lds) {
  __builtin_amdgcn_global_load_lds(
      (const __attribute__((address_space(1))) unsigned int*)g,
      (__attribute__((address_space(3))) unsigned int*)lds, 16, 0, 0);
}

// pack 8 fp32 -> short8 bf16 via RTZ truncation (v_perm_b32, 1 op / 2 elems)
__device__ __forceinline__ short8 pack8_bf16_rtz(f32x4 a, f32x4 b) {
  union { short8 s; unsigned u[4]; } r;
  r.u[0] = __builtin_amdgcn_perm(__float_as_uint(a[1]), __float_as_uint(a[0]), 0x07060302u);
  r.u[1] = __builtin_amdgcn_perm(__float_as_uint(a[3]), __float_as_uint(a[2]), 0x07060302u);
  r.u[2] = __builtin_amdgcn_perm(__float_as_uint(b[1]), __float_as_uint(b[0]), 0x07060302u);
  r.u[3] = __builtin_amdgcn_perm(__float_as_uint(b[3]), __float_as_uint(b[2]), 0x07060302u);
  return r.s;
}

// ---------------------------------------------------------------- router
// wave-per-token: fp32 logits (exact) -> d_out tail; fused x -> bf16.
__global__ __launch_bounds__(256) void router_kernel(
    const float* __restrict__ x, const float* __restrict__ gw,
    unsigned short* __restrict__ xb, float* __restrict__ logits_out) {
  const int wid  = threadIdx.x >> 6;
  const int lane = threadIdx.x & 63;
  const int t = blockIdx.x * 4 + wid;

  const float4* xr = (const float4*)(x + (size_t)t * HD);
  const float4* g4 = (const float4*)gw;
  ushort4* xb4 = (ushort4*)(xb + (size_t)t * HD);

  float acc[NE];
#pragma unroll
  for (int e = 0; e < NE; ++e) acc[e] = 0.f;

#pragma unroll
  for (int it = 0; it < 8; ++it) {
    int idx = it * 64 + lane;
    float4 v = xr[idx];
    ushort4 o;
    o.x = f2bf_rne(v.x); o.y = f2bf_rne(v.y);
    o.z = f2bf_rne(v.z); o.w = f2bf_rne(v.w);
    xb4[idx] = o;
#pragma unroll
    for (int e = 0; e < NE; ++e) {
      float4 g = g4[e * 512 + idx];
      acc[e] += v.x * g.x + v.y * g.y + v.z * g.z + v.w * g.w;
    }
  }
#pragma unroll
  for (int e = 0; e < NE; ++e) {
#pragma unroll
    for (int off = 32; off > 0; off >>= 1)
      acc[e] += __shfl_xor(acc[e], off, 64);
  }
  if (lane == 0) {
    float* lo = logits_out + (size_t)t * NE;
#pragma unroll
    for (int e = 0; e < NE; ++e) lo[e] = acc[e];
  }
}

// ---------------------------------------------------------------- bucket
// 8 blocks (one per expert) x 1024 threads; top-2 from exact fp32 logits.
__global__ __launch_bounds__(1024) void bucket_kernel(
    const float* __restrict__ logits, int* __restrict__ counts,
    int* __restrict__ btok, float* __restrict__ bwt) {
  const int e = blockIdx.x;
  __shared__ int lcount;
  if (threadIdx.x == 0) lcount = 0;
  __syncthreads();
  const int lane = threadIdx.x & 63;

  for (int base = 0; base < TOKENS; base += 1024) {
    int t = base + threadIdx.x;
    const float* lo = logits + (size_t)t * NE;
    float l[NE];
#pragma unroll
    for (int k = 0; k < NE; ++k) l[k] = lo[k];
    int i0 = 0; float b0 = l[0];
#pragma unroll
    for (int k = 1; k < NE; ++k) if (l[k] > b0) { b0 = l[k]; i0 = k; }
    int i1 = -1; float b1 = -3.4e38f;
#pragma unroll
    for (int k = 0; k < NE; ++k) if (k != i0 && l[k] > b1) { b1 = l[k]; i1 = k; }
    float w0 = 1.f / (1.f + __expf(b1 - b0));
    float w1 = 1.f - w0;
#pragma unroll
    for (int s = 0; s < 2; ++s) {
      int  ex = s ? i1 : i0;
      float w = s ? w1 : w0;
      bool p = (ex == e);
      unsigned long long mask = __ballot(p);
      int prefix = __popcll(mask & ((1ull << lane) - 1ull));
      int tot    = __popcll(mask);
      int wb = 0;
      if (lane == 0 && tot) wb = atomicAdd(&lcount, tot);
      wb = __shfl(wb, 0, 64);
      if (p) {
        btok[e * TOKENS + wb + prefix] = t;
        bwt [e * TOKENS + wb + prefix] = w;
      }
    }
  }
  __syncthreads();
  if (threadIdx.x == 0) counts[e * 32] = lcount;
}

// ---------------------------------------------------------------- MoE GEMM
// A: gathered bf16 tokens (async-staged, 16KB). B: expert W staged as RAW
// FP32 via global_load_lds (32KB) — no separate convert pass — converted to
// bf16 at fragment-read time with v_perm RTZ. 48KB LDS -> 3 blocks/CU.
// XCD-affinity: blockIdx%8 == expert.
__global__ __launch_bounds__(256, 3) void moe_gemm_kernel(
    const unsigned short* __restrict__ xb,
    const float* __restrict__ ew,
    const int* __restrict__ counts,
    const int* __restrict__ btok,
    const float* __restrict__ bwt,
    float* __restrict__ out) {
  int d = blockIdx.x;
  int e, coltile, rowtile;
  if (d < 2048) {
    e       = d & 7;          // XCD affinity (dispatch round-robins % 8)
    rowtile = (d >> 3) & 15;
    coltile = d >> 7;
  } else {
    int u = d - 2048;         // overflow: experts with 2048 < cnt <= 4096
    e       = u & 7;
    coltile = (u >> 3) & 15;
    rowtile = 16 + (u >> 7);
  }
  const int cnt = counts[e * 32];
  if (rowtile * 128 >= cnt) return;

  __shared__ unsigned short As[128 * 64];  // 16 KB, bf16
  __shared__ float          Bs[128 * 64];  // 32 KB, fp32

  const int tid  = threadIdx.x;
  const int wid  = tid >> 6;
  const int lane = tid & 63;

  // A staging: 1024 slots of 16B (8 bf16); slot(row,p) holds chunk p^(row&7)
  int a_off[4];
#pragma unroll
  for (int it = 0; it < 4; ++it) {
    int slot = wid * 256 + it * 64 + lane;
    int row  = slot >> 3;
    int ch   = (slot & 7) ^ (row & 7);
    int rc   = rowtile * 128 + row;
    rc = rc < cnt ? rc : cnt - 1;
    a_off[it] = btok[e * TOKENS + rc] * HD + ch * 8;
  }
  // B staging: 2048 slots of 16B (4 fp32); slot(row,p) holds chunk p^(row&15)
  int b_off[8];
#pragma unroll
  for (int it = 0; it < 8; ++it) {
    int slot = wid * 512 + it * 64 + lane;
    int row  = slot >> 4;
    int ch   = (slot & 15) ^ (row & 15);
    b_off[it] = (e * HD + coltile * 128 + row) * HD + ch * 4;
  }

  f32x4 acc[4][4];
#pragma unroll
  for (int i = 0; i < 4; ++i)
#pragma unroll
    for (int j = 0; j < 4; ++j) acc[i][j] = (f32x4){0.f, 0.f, 0.f, 0.f};

  const int quad = lane >> 4;
  const int mrow = lane & 15;
  const int wm2  = wid >> 1;
  const int wn2  = wid & 1;

  int a_rd[2][4];        // bf16-element offsets
  int b_rd[2][4][2];     // fp32-element offsets, two 16B reads per fragment
#pragma unroll
  for (int h = 0; h < 2; ++h)
#pragma unroll
    for (int i = 0; i < 4; ++i) {
      int ra = wm2 * 64 + i * 16 + mrow;
      a_rd[h][i] = ra * 64 + ((4 * h + quad) ^ (ra & 7)) * 8;
      int rb = wn2 * 64 + i * 16 + mrow;
      int c0 = h * 8 + quad * 2;
      b_rd[h][i][0] = rb * 64 + (c0       ^ (rb & 15)) * 4;
      b_rd[h][i][1] = rb * 64 + ((c0 + 1) ^ (rb & 15)) * 4;
    }

  for (int k0 = 0; k0 < HD; k0 += 64) {
#pragma unroll
    for (int it = 0; it < 4; ++it)
      async_load16(xb + a_off[it] + k0, &As[(wid * 256 + it * 64) * 8]);
#pragma unroll
    for (int it = 0; it < 8; ++it)
      async_load16(ew + b_off[it] + k0, &Bs[(wid * 512 + it * 64) * 4]);
    __syncthreads();
#pragma unroll
    for (int h = 0; h < 2; ++h) {
      short8 fa[4], fb[4];
#pragma unroll
      for (int i = 0; i < 4; ++i) {
        fa[i] = *(const short8*)&As[a_rd[h][i]];
        f32x4 g0 = *(const f32x4*)&Bs[b_rd[h][i][0]];
        f32x4 g1 = *(const f32x4*)&Bs[b_rd[h][i][1]];
        fb[i] = pack8_bf16_rtz(g0, g1);
      }
#pragma unroll
      for (int i = 0; i < 4; ++i)
#pragma unroll
        for (int j = 0; j < 4; ++j)
          acc[i][j] = __builtin_amdgcn_mfma_f32_16x16x32_bf16(
              fa[i], fb[j], acc[i][j], 0, 0, 0);
    }
    __syncthreads();
  }

  // epilogue: D layout col=lane&15, row=quad*4+r (m89/m91)
#pragma unroll
  for (int i = 0; i < 4; ++i)
#pragma unroll
    for (int r = 0; r < 4; ++r) {
      int m  = wm2 * 64 + i * 16 + quad * 4 + r;
      int gm = rowtile * 128 + m;
      if (gm < cnt) {
        int   tok = btok[e * TOKENS + gm];
        float w   = bwt [e * TOKENS + gm];
        float* orow = out + (size_t)tok * HD + coltile * 128 + wn2 * 64 + mrow;
#pragma unroll
        for (int j = 0; j < 4; ++j)
          unsafeAtomicAdd(orow + j * 16, w * acc[i][j][r]);
      }
    }
}

// ---------------------------------------------------------------- launch
extern "C" void kernel_launch(void* const* d_in, const int* in_sizes, int n_in,
                              void* d_out, int out_size, void* d_ws, size_t ws_size,
                              hipStream_t stream) {
  const float* x  = (const float*)d_in[0];   // [8192, 2048]
  const float* gw = (const float*)d_in[1];   // [8, 2048]
  const float* ew = (const float*)d_in[2];   // [8, 2048, 2048]
  float* out = (float*)d_out;                // [8192*2048] ++ [8192*8]

  char* ws = (char*)d_ws;
  unsigned short* xb = (unsigned short*)ws;              // 33,554,432 B
  int*   counts = (int*)(ws + 33554432u);                // 1,024 B
  int*   btok   = (int*)(ws + 33555456u);                // 262,144 B
  float* bwt    = (float*)(ws + 33817600u);              // 262,144 B

  float* logits = out + (size_t)TOKENS * HD;

  hipMemsetAsync(out, 0, (size_t)TOKENS * HD * sizeof(float), stream);
  router_kernel<<<TOKENS / 4, 256, 0, stream>>>(x, gw, xb, logits);
  bucket_kernel<<<NE, 1024, 0, stream>>>(logits, counts, btok, bwt);
  moe_gemm_kernel<<<4096, 256, 0, stream>>>(xb, ew, counts, btok, bwt, out);
}

// Round 4
// 473.852 us; speedup vs baseline: 1.1009x; 1.1009x over previous
//
#include <hip/hip_runtime.h>
#include <hip/hip_bf16.h>
#include <stdint.h>

#define TOKENS 8192
#define HD     2048
#define NE     8

typedef __attribute__((ext_vector_type(8)))  short short8;
typedef __attribute__((ext_vector_type(8)))  unsigned short ushort8v;
typedef __attribute__((ext_vector_type(4)))  float f32x4;
typedef __attribute__((ext_vector_type(16))) float f32x16;

__device__ __forceinline__ unsigned short f2bf_rne(float f) {
  union { float f; unsigned u; } v; v.f = f;
  unsigned u = v.u;
  return (unsigned short)((u + 0x7fffu + ((u >> 16) & 1u)) >> 16);
}

__device__ __forceinline__ void async_load16(const void* g, void* lds) {
  __builtin_amdgcn_global_load_lds(
      (const __attribute__((address_space(1))) unsigned int*)g,
      (__attribute__((address_space(3))) unsigned int*)lds, 16, 0, 0);
}

// ---------------------------------------------------------------- prep
// Fused: blocks 0..2047 = router (wave-per-token fp32 logits + x->bf16),
// blocks 2048..6143 = expert-W fp32->bf16 convert. Both memory-bound;
// fusing overlaps them in one dispatch.
__global__ __launch_bounds__(256) void prep_kernel(
    const float* __restrict__ x, const float* __restrict__ gw,
    const float* __restrict__ ew, unsigned short* __restrict__ xb,
    unsigned short* __restrict__ wb, float* __restrict__ logits_out) {
  if (blockIdx.x >= 2048) {
    // ---- convert W: 4 iters/thread over 4,194,304 ushort8 units
    int i = (blockIdx.x - 2048) * 256 + threadIdx.x;
    const int n8 = NE * HD * HD / 8;
    const int stride = 4096 * 256;
    const float4* s4 = (const float4*)ew;
    ushort8v* d8 = (ushort8v*)wb;
    for (; i < n8; i += stride) {
      float4 a = s4[i * 2], b = s4[i * 2 + 1];
      ushort8v o;
      o[0] = f2bf_rne(a.x); o[1] = f2bf_rne(a.y);
      o[2] = f2bf_rne(a.z); o[3] = f2bf_rne(a.w);
      o[4] = f2bf_rne(b.x); o[5] = f2bf_rne(b.y);
      o[6] = f2bf_rne(b.z); o[7] = f2bf_rne(b.w);
      d8[i] = o;
    }
    return;
  }
  // ---- router
  const int wid  = threadIdx.x >> 6;
  const int lane = threadIdx.x & 63;
  const int t = blockIdx.x * 4 + wid;

  const float4* xr = (const float4*)(x + (size_t)t * HD);
  const float4* g4 = (const float4*)gw;
  ushort4* xb4 = (ushort4*)(xb + (size_t)t * HD);

  float acc[NE];
#pragma unroll
  for (int e = 0; e < NE; ++e) acc[e] = 0.f;

#pragma unroll
  for (int it = 0; it < 8; ++it) {
    int idx = it * 64 + lane;
    float4 v = xr[idx];
    ushort4 o;
    o.x = f2bf_rne(v.x); o.y = f2bf_rne(v.y);
    o.z = f2bf_rne(v.z); o.w = f2bf_rne(v.w);
    xb4[idx] = o;
#pragma unroll
    for (int e = 0; e < NE; ++e) {
      float4 g = g4[e * 512 + idx];
      acc[e] += v.x * g.x + v.y * g.y + v.z * g.z + v.w * g.w;
    }
  }
#pragma unroll
  for (int e = 0; e < NE; ++e) {
#pragma unroll
    for (int off = 32; off > 0; off >>= 1)
      acc[e] += __shfl_xor(acc[e], off, 64);
  }
  if (lane == 0) {
    float* lo = logits_out + (size_t)t * NE;
#pragma unroll
    for (int e = 0; e < NE; ++e) lo[e] = acc[e];
  }
}

// ---------------------------------------------------------------- bucket
// top-2 from exact fp32 logits; btok entry = (slot<<13)|token so the gemm
// knows primary (slot0 -> fp32 direct to out) vs secondary (slot1 -> bf16 ws).
__global__ __launch_bounds__(1024) void bucket_kernel(
    const float* __restrict__ logits, int* __restrict__ counts,
    int* __restrict__ btok, float* __restrict__ bwt) {
  const int e = blockIdx.x;
  __shared__ int lcount;
  if (threadIdx.x == 0) lcount = 0;
  __syncthreads();
  const int lane = threadIdx.x & 63;

  for (int base = 0; base < TOKENS; base += 1024) {
    int t = base + threadIdx.x;
    const float* lo = logits + (size_t)t * NE;
    float l[NE];
#pragma unroll
    for (int k = 0; k < NE; ++k) l[k] = lo[k];
    int i0 = 0; float b0 = l[0];
#pragma unroll
    for (int k = 1; k < NE; ++k) if (l[k] > b0) { b0 = l[k]; i0 = k; }
    int i1 = -1; float b1 = -3.4e38f;
#pragma unroll
    for (int k = 0; k < NE; ++k) if (k != i0 && l[k] > b1) { b1 = l[k]; i1 = k; }
    float w0 = 1.f / (1.f + __expf(b1 - b0));
    float w1 = 1.f - w0;
#pragma unroll
    for (int s = 0; s < 2; ++s) {
      int  ex = s ? i1 : i0;
      float w = s ? w1 : w0;
      bool p = (ex == e);
      unsigned long long mask = __ballot(p);
      int prefix = __popcll(mask & ((1ull << lane) - 1ull));
      int tot    = __popcll(mask);
      int wb = 0;
      if (lane == 0 && tot) wb = atomicAdd(&lcount, tot);
      wb = __shfl(wb, 0, 64);
      if (p) {
        btok[e * TOKENS + wb + prefix] = t | (s << 13);
        bwt [e * TOKENS + wb + prefix] = w;
      }
    }
  }
  __syncthreads();
  if (threadIdx.x == 0) counts[e * 32] = lcount;
}

// ---------------------------------------------------------------- MoE GEMM
// R2 staging (bf16 A gather + bf16 W, async global_load_lds 16B, XOR swizzle,
// 32KB LDS), but compute via mfma_f32_32x32x16_bf16 (2x2 frags/wave: 16 MFMA
// + 16 ds_read_b128 per K-step vs 32+16). Epilogue: plain stores into slot
// buffers — no atomics, no memset.
__global__ __launch_bounds__(256, 4) void moe_gemm_kernel(
    const unsigned short* __restrict__ xb,
    const unsigned short* __restrict__ wb,
    const int* __restrict__ counts,
    const int* __restrict__ btok,
    const float* __restrict__ bwt,
    float* __restrict__ out,
    unsigned short* __restrict__ slot1) {
  int d = blockIdx.x;
  int e, coltile, rowtile;
  if (d < 2048) {
    e       = d & 7;          // XCD affinity (dispatch round-robins % 8)
    rowtile = (d >> 3) & 15;
    coltile = d >> 7;
  } else {
    int u = d - 2048;         // overflow: experts with 2048 < cnt <= 4096
    e       = u & 7;
    coltile = (u & 127) >> 3;
    rowtile = 16 + (u >> 7);
  }
  const int cnt = counts[e * 32];
  if (rowtile * 128 >= cnt) return;

  __shared__ unsigned short As[128 * 64];   // 16 KB
  __shared__ unsigned short Bs[128 * 64];   // 16 KB

  const int tid  = threadIdx.x;
  const int wid  = tid >> 6;
  const int lane = tid & 63;

  // staging: 1024 16B slots/tile; LDS slot(row,p) holds chunk p^(row&7)
  int a_off[4], b_off[4];
#pragma unroll
  for (int it = 0; it < 4; ++it) {
    int slot = wid * 256 + it * 64 + lane;
    int row  = slot >> 3;
    int ch   = (slot & 7) ^ (row & 7);
    int rc   = rowtile * 128 + row;
    rc = rc < cnt ? rc : cnt - 1;            // clamp pad rows
    a_off[it] = (btok[e * TOKENS + rc] & (TOKENS - 1)) * HD + ch * 8;
    b_off[it] = (e * HD + coltile * 128 + row) * HD + ch * 8;
  }

  f32x16 acc[2][2];
#pragma unroll
  for (int i = 0; i < 2; ++i)
#pragma unroll
    for (int j = 0; j < 2; ++j)
#pragma unroll
      for (int r = 0; r < 16; ++r) acc[i][j][r] = 0.f;

  const int l5  = lane >> 5;   // k-half
  const int ln  = lane & 31;   // m/n within 32-tile
  const int wm2 = wid >> 1;
  const int wn2 = wid & 1;

  // fragment read offsets: A[m][k]: m=ln, k=(l5)*8+j within K-chunk kc*16
  int a_rd[2][4], b_rd[2][4];
#pragma unroll
  for (int t = 0; t < 2; ++t)
#pragma unroll
    for (int kc = 0; kc < 4; ++kc) {
      int ra = wm2 * 64 + t * 32 + ln;
      a_rd[t][kc] = ra * 64 + ((kc * 2 + l5) ^ (ra & 7)) * 8;
      int rb = wn2 * 64 + t * 32 + ln;
      b_rd[t][kc] = rb * 64 + ((kc * 2 + l5) ^ (rb & 7)) * 8;
    }

  for (int k0 = 0; k0 < HD; k0 += 64) {
#pragma unroll
    for (int it = 0; it < 4; ++it) {
      async_load16(xb + a_off[it] + k0, &As[(wid * 256 + it * 64) * 8]);
      async_load16(wb + b_off[it] + k0, &Bs[(wid * 256 + it * 64) * 8]);
    }
    __syncthreads();
    short8 fa[2][4], fb[2][4];
#pragma unroll
    for (int t = 0; t < 2; ++t)
#pragma unroll
      for (int kc = 0; kc < 4; ++kc) {
        fa[t][kc] = *(const short8*)&As[a_rd[t][kc]];
        fb[t][kc] = *(const short8*)&Bs[b_rd[t][kc]];
      }
#pragma unroll
    for (int kc = 0; kc < 4; ++kc)
#pragma unroll
      for (int i = 0; i < 2; ++i)
#pragma unroll
        for (int j = 0; j < 2; ++j)
          acc[i][j] = __builtin_amdgcn_mfma_f32_32x32x16_bf16(
              fa[i][kc], fb[j][kc], acc[i][j], 0, 0, 0);
    __syncthreads();
  }

  // epilogue: 32x32 C/D layout col=lane&31, row=(reg&3)+8*(reg>>2)+4*(lane>>5)
  // (m74/m101). slot0 -> fp32 direct into out; slot1 -> bf16 scratch.
#pragma unroll
  for (int ti = 0; ti < 2; ++ti)
#pragma unroll
    for (int rg = 0; rg < 16; ++rg) {
      int row = (rg & 3) + 8 * (rg >> 2) + 4 * l5;
      int gm  = rowtile * 128 + wm2 * 64 + ti * 32 + row;
      if (gm < cnt) {
        int   dv = btok[e * TOKENS + gm];
        float w  = bwt [e * TOKENS + gm];
        int   nb = coltile * 128 + wn2 * 64 + ln;
        float v0 = w * acc[ti][0][rg];
        float v1 = w * acc[ti][1][rg];
        if (dv < TOKENS) {
          float* orow = out + (size_t)dv * HD + nb;
          orow[0]  = v0;
          orow[32] = v1;
        } else {
          unsigned short* srow = slot1 + (size_t)(dv - TOKENS) * HD + nb;
          srow[0]  = f2bf_rne(v0);
          srow[32] = f2bf_rne(v1);
        }
      }
    }
}

// ---------------------------------------------------------------- combine
// out[t] += slot1[t] (bf16 -> fp32). 1 unit of 8 elems per thread.
__global__ __launch_bounds__(256) void combine_kernel(
    const unsigned short* __restrict__ s1, float* __restrict__ out) {
  size_t u = (size_t)blockIdx.x * 256 + threadIdx.x;
  ushort8v sv = ((const ushort8v*)s1)[u];
  float4* o = (float4*)out + u * 2;
  float4 a = o[0], b = o[1];
  a.x += __uint_as_float((unsigned)sv[0] << 16);
  a.y += __uint_as_float((unsigned)sv[1] << 16);
  a.z += __uint_as_float((unsigned)sv[2] << 16);
  a.w += __uint_as_float((unsigned)sv[3] << 16);
  b.x += __uint_as_float((unsigned)sv[4] << 16);
  b.y += __uint_as_float((unsigned)sv[5] << 16);
  b.z += __uint_as_float((unsigned)sv[6] << 16);
  b.w += __uint_as_float((unsigned)sv[7] << 16);
  o[0] = a; o[1] = b;
}

// ---------------------------------------------------------------- launch
extern "C" void kernel_launch(void* const* d_in, const int* in_sizes, int n_in,
                              void* d_out, int out_size, void* d_ws, size_t ws_size,
                              hipStream_t stream) {
  const float* x  = (const float*)d_in[0];   // [8192, 2048]
  const float* gw = (const float*)d_in[1];   // [8, 2048]
  const float* ew = (const float*)d_in[2];   // [8, 2048, 2048]
  float* out = (float*)d_out;                // [8192*2048] ++ [8192*8]

  char* ws = (char*)d_ws;
  unsigned short* xb    = (unsigned short*)ws;                  // 33,554,432 B
  unsigned short* wb    = (unsigned short*)(ws + 33554432u);    // 67,108,864 B
  unsigned short* slot1 = (unsigned short*)(ws + 100663296u);   // 33,554,432 B
  int*   counts = (int*)(ws + 134217728u);                      // 1,024 B
  int*   btok   = (int*)(ws + 134218752u);                      // 262,144 B
  float* bwt    = (float*)(ws + 134480896u);                    // 262,144 B

  float* logits = out + (size_t)TOKENS * HD;

  prep_kernel<<<6144, 256, 0, stream>>>(x, gw, ew, xb, wb, logits);
  bucket_kernel<<<NE, 1024, 0, stream>>>(logits, counts, btok, bwt);
  moe_gemm_kernel<<<4096, 256, 0, stream>>>(xb, wb, counts, btok, bwt, out, slot1);
  combine_kernel<<<8192, 256, 0, stream>>>(slot1, out);
}